// Round 4
// baseline (146.889 us; speedup 1.0000x reference)
//
#include <hip/hip_runtime.h>
#include <stdint.h>

#define THREADS 256
#define TM 128
#define TN 128
#define BK 64
#define MAXTILES 40
#define NE 8
#define BB 4
#define SS 512
#define KK 2
#define II 1024
#define DD 2048
#define NTOK (BB * SS)         // 2048
#define NASSIGN (BB * KK * SS) // 4096

// convert grid: one 8-float chunk per thread
#define CH_X (NTOK * II / 8)      // 262144
#define CH_P (NE * DD * II / 8)   // 2097152
#define CB_X (CH_X / 256)         // 1024 blocks
#define CB_P (CH_P / 256)         // 8192 blocks
#define CB_TOTAL (CB_X + 2 * CB_P) // 17408 blocks

typedef unsigned short u16;
typedef __attribute__((ext_vector_type(8))) __bf16 bf16x8;
typedef __attribute__((ext_vector_type(4))) float f32x4;
typedef __attribute__((ext_vector_type(4))) unsigned int u32x4;

__device__ __forceinline__ u16 f32_to_bf16(float f) {
    unsigned int u = __builtin_bit_cast(unsigned int, f);
    unsigned int r = u + 0x7FFFu + ((u >> 16) & 1u);
    return (u16)(r >> 16);
}

__device__ __forceinline__ void gload16(const void* g, void* l) {
    __builtin_amdgcn_global_load_lds(
        (const __attribute__((address_space(1))) unsigned int*)g,
        (__attribute__((address_space(3))) unsigned int*)l, 16, 0, 0);
}

// ---------------- setup: bucket assignments by expert ----------------
__global__ void setup_kernel(const void* __restrict__ ens_raw,
                             const float* __restrict__ weights,
                             int* __restrict__ meta,
                             int* __restrict__ tok,
                             float* __restrict__ wgt) {
    __shared__ int s_cnt[NE];
    __shared__ int s_cur[NE];
    __shared__ int s_flag;
    const int t = threadIdx.x;
    if (t < NE) s_cnt[t] = 0;
    if (t == 0) s_flag = 0;
    __syncthreads();

    // dtype detect: int64 ensembles (vals 0..7) -> all odd 32-bit words zero
    const unsigned int* w32 = (const unsigned int*)ens_raw;
    unsigned int f = 0;
    for (int i = t; i < NASSIGN / 2; i += THREADS) f |= w32[2 * i + 1];
    if (f) atomicOr(&s_flag, 1);
    __syncthreads();
    const bool is32 = (s_flag != 0);
    const int* e32 = (const int*)ens_raw;
    const long long* e64 = (const long long*)ens_raw;

    for (int a = t; a < NASSIGN; a += THREADS) {
        int e = is32 ? e32[a] : (int)e64[a];
        atomicAdd(&s_cnt[e & 7], 1);
    }
    __syncthreads();

    if (t == 0) {
        int pb = 0, nt = 0;
        for (int e = 0; e < NE; e++) {
            int c = s_cnt[e];
            meta[8 + e] = c;
            meta[16 + e] = pb;
            s_cur[e] = pb;
            int ntile = (c + TM - 1) / TM;
            for (int i = 0; i < ntile; i++) {
                meta[32 + nt] = e;           // tile -> expert
                meta[80 + nt] = pb + i * TM; // tile -> slot base
                meta[128 + nt] = pb + c;     // tile -> real end
                nt++;
            }
            pb += ntile * TM;
        }
        meta[0] = nt;
        meta[1] = pb;
    }
    __syncthreads();

    for (int a = t; a < NASSIGN; a += THREADS) {
        int e = is32 ? e32[a] : (int)e64[a];
        e &= 7;
        int slot = atomicAdd(&s_cur[e], 1);
        int b = a >> 10;      // a / (K*S)
        int s = a & (SS - 1); // a % S
        tok[slot] = b * SS + s;
        wgt[slot] = weights[a];
    }
    __syncthreads();

    // pad fill
    for (int e = 0; e < NE; e++) {
        int st = meta[16 + e] + meta[8 + e];
        int en = (e < NE - 1) ? meta[16 + e + 1] : meta[1];
        for (int i = st + t; i < en; i += THREADS) {
            tok[i] = 0;
            wgt[i] = 0.f;
        }
    }
}

// ---------------- f32 -> bf16: flat, branch-once, nontemporal loads --------
__global__ __launch_bounds__(256)
void convert3(const float* __restrict__ x,
              const float* __restrict__ pin,
              const float* __restrict__ pout,
              u16* __restrict__ xb,
              u16* __restrict__ pb1,
              u16* __restrict__ pb2) {
    const int b = blockIdx.x;
    const float* s;
    u16* d;
    int base;
    if (b < CB_X)            { s = x;    d = xb;  base = b << 8; }
    else if (b < CB_X + CB_P){ s = pin;  d = pb1; base = (b - CB_X) << 8; }
    else                     { s = pout; d = pb2; base = (b - CB_X - CB_P) << 8; }
    const size_t k = (size_t)base + threadIdx.x;
    const f32x4* s4 = (const f32x4*)s;
    f32x4 a = __builtin_nontemporal_load(&s4[2 * k]);
    f32x4 c = __builtin_nontemporal_load(&s4[2 * k + 1]);
    union { u16 u[8]; u32x4 v; } o;
    o.u[0] = f32_to_bf16(a[0]); o.u[1] = f32_to_bf16(a[1]);
    o.u[2] = f32_to_bf16(a[2]); o.u[3] = f32_to_bf16(a[3]);
    o.u[4] = f32_to_bf16(c[0]); o.u[5] = f32_to_bf16(c[1]);
    o.u[6] = f32_to_bf16(c[2]); o.u[7] = f32_to_bf16(c[3]);
    *(u32x4*)(d + 8 * k) = o.v;
}

// ---------------- grouped GEMM (128^2 2-barrier + XCD-chunked swizzle) -----
// MODE 0: h[slot] = relu(x[tok[slot]] @ proj_in[e]^T)      (M x 1024) -> (M x 2048)
//         grid 640 = 8 XCD-chunks of (10 tiles x 8 cols)
// MODE 1: out[tok[slot]] += wgt * (h[slot] @ proj_out[e]^T) (M x 2048) -> (M x 1024)
//         grid 320 = 8 XCD-chunks of (5 tiles x 8 cols)
template <int MODE>
__global__ __launch_bounds__(THREADS)
void gemm_kernel(const u16* __restrict__ Abase,
                 const u16* __restrict__ Bbase,
                 const int* __restrict__ meta,
                 const int* __restrict__ tok,
                 const float* __restrict__ wgt,
                 u16* __restrict__ hdst,
                 float* __restrict__ outdst) {
    constexpr int Kdim = (MODE == 0) ? II : DD;

    // XCD-aware 2-D chunk decode: XCD = lid & 7 (round-robin dispatch heuristic)
    const int lid = blockIdx.x;
    const int g = lid & 7;
    const int i = lid >> 3;
    int tile, colt;
    if (MODE == 0) {
        const int gy = g >> 1, gx = g & 1;
        tile = gy * 10 + (i % 10);
        colt = gx * 8 + (i / 10);
    } else {
        tile = g * 5 + (i % 5);
        colt = i / 5;
    }
    if (tile >= meta[0]) return;

    const int e = meta[32 + tile];
    const int sbase = meta[80 + tile];
    const int rend = meta[128 + tile];
    const int colbase = colt * TN;

    __shared__ u16 ldsA[TM * BK];
    __shared__ u16 ldsB[TN * BK];

    const int lane = threadIdx.x & 63;
    const int wv = threadIdx.x >> 6;

    const u16* Bp = Bbase + (size_t)e * (size_t)(DD * II) + (size_t)colbase * Kdim;

    // staging: 16B chunk c -> LDS byte 16c (linear dest); source pre-swizzled
    int aoff[4], boff[4], ldst[4];
#pragma unroll
    for (int j = 0; j < 4; j++) {
        int c = (j * 4 + wv) * 64 + lane;
        int row = c >> 3;
        int s = (c & 7) ^ (row & 7); // inverse-swizzled source slot
        ldst[j] = (j * 4 + wv) * 512;
        if (MODE == 0) {
            aoff[j] = tok[sbase + row] * II + s * 8;
        } else {
            aoff[j] = (sbase + row) * DD + s * 8;
        }
        boff[j] = row * Kdim + s * 8;
    }

    f32x4 acc[4][4];
#pragma unroll
    for (int mi = 0; mi < 4; mi++)
#pragma unroll
        for (int ni = 0; ni < 4; ni++)
            acc[mi][ni] = (f32x4){0.f, 0.f, 0.f, 0.f};

    const int wr = (wv >> 1) * 64;
    const int wc = (wv & 1) * 64;

    for (int ks = 0; ks < Kdim / BK; ks++) {
        const int kof = ks * BK;
#pragma unroll
        for (int j = 0; j < 4; j++)
            gload16(Abase + aoff[j] + kof, &ldsA[ldst[j]]);
#pragma unroll
        for (int j = 0; j < 4; j++)
            gload16(Bp + boff[j] + kof, &ldsB[ldst[j]]);
        __syncthreads(); // drains vmcnt before LDS reads

#pragma unroll
        for (int kk = 0; kk < 2; kk++) {
            bf16x8 af[4], bfr[4];
#pragma unroll
            for (int mi = 0; mi < 4; mi++) {
                int row = wr + mi * 16 + (lane & 15);
                int slot = (kk * 4 + (lane >> 4)) ^ (row & 7);
                af[mi] = *(const bf16x8*)&ldsA[row * BK + slot * 8];
            }
#pragma unroll
            for (int ni = 0; ni < 4; ni++) {
                int row = wc + ni * 16 + (lane & 15);
                int slot = (kk * 4 + (lane >> 4)) ^ (row & 7);
                bfr[ni] = *(const bf16x8*)&ldsB[row * BK + slot * 8];
            }
#pragma unroll
            for (int mi = 0; mi < 4; mi++)
#pragma unroll
                for (int ni = 0; ni < 4; ni++)
                    acc[mi][ni] = __builtin_amdgcn_mfma_f32_16x16x32_bf16(
                        af[mi], bfr[ni], acc[mi][ni], 0, 0, 0);
        }
        __syncthreads();
    }

    if (MODE == 0) {
#pragma unroll
        for (int mi = 0; mi < 4; mi++) {
#pragma unroll
            for (int r = 0; r < 4; r++) {
                int row = wr + mi * 16 + (lane >> 4) * 4 + r;
                size_t rowoff = (size_t)(sbase + row) * DD;
#pragma unroll
                for (int ni = 0; ni < 4; ni++) {
                    int col = colbase + wc + ni * 16 + (lane & 15);
                    float v = acc[mi][ni][r];
                    v = v > 0.f ? v : 0.f;
                    hdst[rowoff + col] = f32_to_bf16(v);
                }
            }
        }
    } else {
#pragma unroll
        for (int mi = 0; mi < 4; mi++) {
#pragma unroll
            for (int r = 0; r < 4; r++) {
                int row = wr + mi * 16 + (lane >> 4) * 4 + r;
                int slot = sbase + row;
                if (slot < rend) { // skip padding rows
                    float w = wgt[slot];
                    size_t obase = (size_t)tok[slot] * II;
#pragma unroll
                    for (int ni = 0; ni < 4; ni++) {
                        int col = colbase + wc + ni * 16 + (lane & 15);
                        atomicAdd(&outdst[obase + col], acc[mi][ni][r] * w);
                    }
                }
            }
        }
    }
}

// ---------------- launch ----------------
extern "C" void kernel_launch(void* const* d_in, const int* in_sizes, int n_in,
                              void* d_out, int out_size, void* d_ws, size_t ws_size,
                              hipStream_t stream) {
    const float* x = (const float*)d_in[0];
    const float* weights = (const float*)d_in[1];
    const void* ens = d_in[2];
    const float* pin = (const float*)d_in[3];
    const float* pout = (const float*)d_in[4];
    float* out = (float*)d_out;

    char* ws = (char*)d_ws;
    int*   meta    = (int*)(ws);            // 1 KB
    int*   tok     = (int*)(ws + 1024);     // 20 KB
    float* wgt     = (float*)(ws + 21504);  // 20 KB   -> 41984
    u16*   x_bf    = (u16*)(ws + 41984);    // 4 MB    -> 4236288
    u16*   pin_bf  = (u16*)(ws + 4236288);  // 33.5 MB -> 37790720
    u16*   pout_bf = (u16*)(ws + 37790720); // 33.5 MB -> 71345152
    u16*   h       = (u16*)(ws + 71345152); // 21 MB   -> 92316672 total

    setup_kernel<<<dim3(1), dim3(THREADS), 0, stream>>>(ens, weights, meta, tok, wgt);

    hipMemsetAsync(d_out, 0, (size_t)out_size * sizeof(float), stream);

    convert3<<<dim3(CB_TOTAL), dim3(256), 0, stream>>>(x, pin, pout, x_bf, pin_bf, pout_bf);

    gemm_kernel<0><<<dim3(MAXTILES * (DD / TN)), dim3(THREADS), 0, stream>>>(
        x_bf, pin_bf, meta, tok, wgt, h, nullptr);

    gemm_kernel<1><<<dim3(MAXTILES * (II / TN)), dim3(THREADS), 0, stream>>>(
        h, pout_bf, meta, tok, wgt, nullptr, out);
}

// Round 5
// 134.782 us; speedup vs baseline: 1.0898x; 1.0898x over previous
//
#include <hip/hip_runtime.h>
#include <stdint.h>

#define THREADS 512
#define BM 256
#define BN 128
#define BK 64
#define MAXT 24
#define NE 8
#define BB 4
#define SS 512
#define KK 2
#define II 1024
#define DD 2048
#define NTOK (BB * SS)         // 2048
#define NASSIGN (BB * KK * SS) // 4096

// convert grid: one 8-float chunk per thread
#define CH_X (NTOK * II / 8)
#define CH_P (NE * DD * II / 8)
#define CB_X (CH_X / 256)
#define CB_P (CH_P / 256)
#define CB_TOTAL (CB_X + 2 * CB_P)

typedef unsigned short u16;
typedef __attribute__((ext_vector_type(8))) __bf16 bf16x8;
typedef __attribute__((ext_vector_type(4))) float f32x4;
typedef __attribute__((ext_vector_type(4))) unsigned int u32x4;

__device__ __forceinline__ u16 f32_to_bf16(float f) {
    unsigned int u = __builtin_bit_cast(unsigned int, f);
    unsigned int r = u + 0x7FFFu + ((u >> 16) & 1u);
    return (u16)(r >> 16);
}

__device__ __forceinline__ void gload16(const void* g, void* l) {
    __builtin_amdgcn_global_load_lds(
        (const __attribute__((address_space(1))) unsigned int*)g,
        (__attribute__((address_space(3))) unsigned int*)l, 16, 0, 0);
}

// ---------------- setup: bucket assignments by expert, 256-row tiles -------
__global__ void setup_kernel(const void* __restrict__ ens_raw,
                             const float* __restrict__ weights,
                             int* __restrict__ meta,
                             int* __restrict__ tok,
                             float* __restrict__ wgt) {
    __shared__ int s_cnt[NE];
    __shared__ int s_cur[NE];
    __shared__ int s_flag;
    const int t = threadIdx.x;
    if (t < NE) s_cnt[t] = 0;
    if (t == 0) s_flag = 0;
    __syncthreads();

    // dtype detect: int64 ensembles (vals 0..7) -> all odd 32-bit words zero
    const unsigned int* w32 = (const unsigned int*)ens_raw;
    unsigned int f = 0;
    for (int i = t; i < NASSIGN / 2; i += 256) f |= w32[2 * i + 1];
    if (f) atomicOr(&s_flag, 1);
    __syncthreads();
    const bool is32 = (s_flag != 0);
    const int* e32 = (const int*)ens_raw;
    const long long* e64 = (const long long*)ens_raw;

    for (int a = t; a < NASSIGN; a += 256) {
        int e = is32 ? e32[a] : (int)e64[a];
        atomicAdd(&s_cnt[e & 7], 1);
    }
    __syncthreads();

    if (t == 0) {
        int pb = 0, nt = 0;
        for (int e = 0; e < NE; e++) {
            int c = s_cnt[e];
            meta[8 + e] = c;
            meta[16 + e] = pb;
            s_cur[e] = pb;
            int n128 = (c + 127) >> 7;
            int pe = pb + n128 * 128;
            for (int i2 = 0; i2 < n128; i2 += 2) {
                meta[32 + nt] = e;            // expert
                meta[64 + nt] = pb + i2 * 128; // slot base (256-row tile)
                meta[96 + nt] = pb + c;        // real end (atomic guard)
                meta[128 + nt] = pe;           // pad end  (h-write guard)
                nt++;
            }
            pb = pe;
        }
        meta[0] = nt;
        meta[1] = pb;
    }
    __syncthreads();

    for (int a = t; a < NASSIGN; a += 256) {
        int e = is32 ? e32[a] : (int)e64[a];
        e &= 7;
        int slot = atomicAdd(&s_cur[e], 1);
        int b = a >> 10;
        int s = a & (SS - 1);
        tok[slot] = b * SS + s;
        wgt[slot] = weights[a];
    }
    __syncthreads();

    // pad fill
    for (int e = 0; e < NE; e++) {
        int st = meta[16 + e] + meta[8 + e];
        int en = (e < NE - 1) ? meta[16 + e + 1] : meta[1];
        for (int i = st + t; i < en; i += 256) {
            tok[i] = 0;
            wgt[i] = 0.f;
        }
    }
}

// ---------------- f32 -> bf16: flat, branch-once, nontemporal loads --------
__global__ __launch_bounds__(256)
void convert3(const float* __restrict__ x,
              const float* __restrict__ pin,
              const float* __restrict__ pout,
              u16* __restrict__ xb,
              u16* __restrict__ pb1,
              u16* __restrict__ pb2) {
    const int b = blockIdx.x;
    const float* s;
    u16* d;
    int base;
    if (b < CB_X)            { s = x;    d = xb;  base = b << 8; }
    else if (b < CB_X + CB_P){ s = pin;  d = pb1; base = (b - CB_X) << 8; }
    else                     { s = pout; d = pb2; base = (b - CB_X - CB_P) << 8; }
    const size_t k = (size_t)base + threadIdx.x;
    const f32x4* s4 = (const f32x4*)s;
    f32x4 a = __builtin_nontemporal_load(&s4[2 * k]);
    f32x4 c = __builtin_nontemporal_load(&s4[2 * k + 1]);
    union { u16 u[8]; u32x4 v; } o;
    o.u[0] = f32_to_bf16(a[0]); o.u[1] = f32_to_bf16(a[1]);
    o.u[2] = f32_to_bf16(a[2]); o.u[3] = f32_to_bf16(a[3]);
    o.u[4] = f32_to_bf16(c[0]); o.u[5] = f32_to_bf16(c[1]);
    o.u[6] = f32_to_bf16(c[2]); o.u[7] = f32_to_bf16(c[3]);
    *(u32x4*)(d + 8 * k) = o.v;
}

// ---------------- grouped GEMM: 256x128 tile, triple-buffer, counted vmcnt -
// MODE 0: h[slot] = relu(x[tok[slot]] @ proj_in[e]^T)   K=1024, NT=16
// MODE 1: out[tok[slot]] += wgt*(h[slot] @ proj_out[e]^T) K=2048, NT=32
// 8 waves: wr = wv>>1 (4 x 64-row stripes), wc = wv&1 (2 x 64-col stripes)
// LDS: 3 buffers x (A 32KB + B 16KB) = 144KB, 1 block/CU, 2 waves/SIMD
template <int MODE>
__global__ __launch_bounds__(THREADS, 2)
void gemm256(const u16* __restrict__ Abase,
             const u16* __restrict__ Bbase,
             const int* __restrict__ meta,
             const int* __restrict__ tok,
             const float* __restrict__ wgt,
             u16* __restrict__ hdst,
             float* __restrict__ outdst) {
    constexpr int Kdim = (MODE == 0) ? II : DD;
    constexpr int NT = Kdim / BK; // 16 or 32
    __shared__ char smem[3 * 49152];

    // XCD-chunked decode: XCD g owns 3 consecutive tiles x all col-blocks
    const int lid = blockIdx.x;
    const int g = lid & 7;
    const int i = lid >> 3;
    const int tile = g * 3 + (i % 3);
    const int colt = i / 3;
    if (tile >= meta[0]) return;

    const int e     = meta[32 + tile];
    const int sbase = meta[64 + tile];
    const int rend  = meta[96 + tile];
    const int wend  = meta[128 + tile];
    const int padmax = meta[1];
    const int colbase = colt * BN;

    const int tid = threadIdx.x;
    const int lane = tid & 63;
    const int wv = tid >> 6;
    const int wr = wv >> 1;
    const int wc = wv & 1;

    const u16* Bp = Bbase + (size_t)e * (size_t)(DD * II) + (size_t)colbase * Kdim;

    // staging maps: A 2048 chunks (4/thread), B 1024 chunks (2/thread)
    int aoff[4], boff[2], adst[4], bdst[2];
#pragma unroll
    for (int j = 0; j < 4; j++) {
        int c = j * 512 + tid;
        int row = c >> 3;
        int s = (c & 7) ^ (row & 7); // inverse-swizzled source slot
        adst[j] = c * 16;            // byte offset in A region
        int slot = sbase + row;
        if (slot > padmax - 1) slot = padmax - 1; // clamp (discarded rows)
        aoff[j] = (MODE == 0 ? tok[slot] * II : slot * DD) + s * 8;
    }
#pragma unroll
    for (int j = 0; j < 2; j++) {
        int c = j * 512 + tid;
        int row = c >> 3;
        int s = (c & 7) ^ (row & 7);
        bdst[j] = c * 16;
        boff[j] = row * Kdim + s * 8;
    }

    f32x4 acc[4][4];
#pragma unroll
    for (int m = 0; m < 4; m++)
#pragma unroll
        for (int n = 0; n < 4; n++)
            acc[m][n] = (f32x4){0.f, 0.f, 0.f, 0.f};

    auto STAGE = [&](int kt, char* buf) {
        const int kof = kt * BK;
#pragma unroll
        for (int j = 0; j < 4; j++)
            gload16(Abase + aoff[j] + kof, buf + adst[j]);
#pragma unroll
        for (int j = 0; j < 2; j++)
            gload16(Bp + boff[j] + kof, buf + 32768 + bdst[j]);
    };

    auto COMPUTE = [&](const char* buf) {
        const u16* As = (const u16*)buf;
        const u16* Bs = (const u16*)(buf + 32768);
        bf16x8 a[2][4], b[2][4];
#pragma unroll
        for (int kk = 0; kk < 2; kk++) {
#pragma unroll
            for (int m = 0; m < 4; m++) {
                int row = wr * 64 + m * 16 + (lane & 15);
                int slot = (kk * 4 + (lane >> 4)) ^ (row & 7);
                a[kk][m] = *(const bf16x8*)&As[row * 64 + slot * 8];
            }
#pragma unroll
            for (int n = 0; n < 4; n++) {
                int col = wc * 64 + n * 16 + (lane & 15);
                int slot = (kk * 4 + (lane >> 4)) ^ (col & 7);
                b[kk][n] = *(const bf16x8*)&Bs[col * 64 + slot * 8];
            }
        }
        __builtin_amdgcn_s_setprio(1);
#pragma unroll
        for (int m = 0; m < 4; m++)
#pragma unroll
            for (int n = 0; n < 4; n++) {
                acc[m][n] = __builtin_amdgcn_mfma_f32_16x16x32_bf16(
                    a[0][m], b[0][n], acc[m][n], 0, 0, 0);
                acc[m][n] = __builtin_amdgcn_mfma_f32_16x16x32_bf16(
                    a[1][m], b[1][n], acc[m][n], 0, 0, 0);
            }
        __builtin_amdgcn_s_setprio(0);
    };

    char* pA = smem;
    char* pB = smem + 49152;
    char* pC = smem + 98304;

    // prologue: tiles 0,1 staged; wait for tile 0 (retire 6 oldest of 12)
    STAGE(0, pA);
    STAGE(1, pB);
    asm volatile("s_waitcnt vmcnt(6)" ::: "memory");
    __builtin_amdgcn_sched_barrier(0);
    __builtin_amdgcn_s_barrier();
    __builtin_amdgcn_sched_barrier(0);

#pragma unroll 1
    for (int t = 0; t < NT; ++t) {
        if (t + 2 < NT) STAGE(t + 2, pC);
        COMPUTE(pA);
        if (t + 2 < NT) {
            asm volatile("s_waitcnt vmcnt(6)" ::: "memory"); // retire stage(t+1)
        } else if (t + 1 < NT) {
            asm volatile("s_waitcnt vmcnt(0)" ::: "memory"); // tail drain
        }
        __builtin_amdgcn_sched_barrier(0);
        __builtin_amdgcn_s_barrier();
        __builtin_amdgcn_sched_barrier(0);
        char* tmp = pA; pA = pB; pB = pC; pC = tmp;
    }

    if (MODE == 0) {
#pragma unroll
        for (int m = 0; m < 4; m++) {
#pragma unroll
            for (int r = 0; r < 4; r++) {
                int row = wr * 64 + m * 16 + (lane >> 4) * 4 + r;
                int slot = sbase + row;
                if (slot < wend) { // stay inside this expert's pad region
                    size_t ro = (size_t)slot * DD;
#pragma unroll
                    for (int n = 0; n < 4; n++) {
                        int col = colbase + wc * 64 + n * 16 + (lane & 15);
                        float v = acc[m][n][r];
                        v = v > 0.f ? v : 0.f;
                        hdst[ro + col] = f32_to_bf16(v);
                    }
                }
            }
        }
    } else {
#pragma unroll
        for (int m = 0; m < 4; m++) {
#pragma unroll
            for (int r = 0; r < 4; r++) {
                int row = wr * 64 + m * 16 + (lane >> 4) * 4 + r;
                int slot = sbase + row;
                if (slot < rend) { // skip padding rows
                    float w = wgt[slot];
                    size_t obase = (size_t)tok[slot] * II;
#pragma unroll
                    for (int n = 0; n < 4; n++) {
                        int col = colbase + wc * 64 + n * 16 + (lane & 15);
                        atomicAdd(&outdst[obase + col], acc[m][n][r] * w);
                    }
                }
            }
        }
    }
}

// ---------------- launch ----------------
extern "C" void kernel_launch(void* const* d_in, const int* in_sizes, int n_in,
                              void* d_out, int out_size, void* d_ws, size_t ws_size,
                              hipStream_t stream) {
    const float* x = (const float*)d_in[0];
    const float* weights = (const float*)d_in[1];
    const void* ens = d_in[2];
    const float* pin = (const float*)d_in[3];
    const float* pout = (const float*)d_in[4];
    float* out = (float*)d_out;

    char* ws = (char*)d_ws;
    int*   meta    = (int*)(ws);            // 1 KB
    int*   tok     = (int*)(ws + 1024);     // 20 KB
    float* wgt     = (float*)(ws + 21504);  // 20 KB   -> 41984
    u16*   x_bf    = (u16*)(ws + 41984);    // 4 MB    -> 4236288
    u16*   pin_bf  = (u16*)(ws + 4236288);  // 33.5 MB -> 37790720
    u16*   pout_bf = (u16*)(ws + 37790720); // 33.5 MB -> 71345152
    u16*   h       = (u16*)(ws + 71345152); // 21 MB   -> 92316672 total

    setup_kernel<<<dim3(1), dim3(256), 0, stream>>>(ens, weights, meta, tok, wgt);

    hipMemsetAsync(d_out, 0, (size_t)out_size * sizeof(float), stream);

    convert3<<<dim3(CB_TOTAL), dim3(256), 0, stream>>>(x, pin, pout, x_bf, pin_bf, pout_bf);

    // gemm1: 24 tiles x 16 col-blocks, XCD-chunked
    gemm256<0><<<dim3(8 * 3 * 16), dim3(THREADS), 0, stream>>>(
        x_bf, pin_bf, meta, tok, wgt, h, nullptr);

    // gemm2: 24 tiles x 8 col-blocks
    gemm256<1><<<dim3(8 * 3 * 8), dim3(THREADS), 0, stream>>>(
        h, pout_bf, meta, tok, wgt, nullptr, out);
}